// Round 1
// baseline (971.562 us; speedup 1.0000x reference)
//
#include <hip/hip_runtime.h>

#define N_NODES 100000
#define N_EDGES 1600000
#define NB_SCAN 49  // ceil(100000/2048)

// ---------------- CSR build ----------------

__global__ void k_zero(int* __restrict__ p, int n) {
    int i = blockIdx.x * blockDim.x + threadIdx.x;
    if (i < n) p[i] = 0;
}

__global__ void k_count(const int* __restrict__ dst, int* __restrict__ cnt) {
    int e = blockIdx.x * blockDim.x + threadIdx.x;
    if (e < N_EDGES) atomicAdd(&cnt[dst[e]], 1);
}

// per-block (2048 elems) sums
__global__ void k_partial(const int* __restrict__ cnt, int* __restrict__ part) {
    __shared__ int red[256];
    int t = threadIdx.x;
    int base = blockIdx.x * 2048 + t * 8;
    int s = 0;
    if (base < N_NODES) {  // N_NODES % 8 == 0, so base<N implies base+7<N
        const int4* p = (const int4*)(cnt + base);
        int4 a = p[0], b = p[1];
        s = a.x + a.y + a.z + a.w + b.x + b.y + b.z + b.w;
    }
    red[t] = s;
    __syncthreads();
    for (int d = 128; d > 0; d >>= 1) {
        if (t < d) red[t] += red[t + d];
        __syncthreads();
    }
    if (t == 0) part[blockIdx.x] = red[0];
}

// exclusive scan of the NB_SCAN partials (single wave)
__global__ void k_scan_part(int* __restrict__ part, int nb) {
    int lane = threadIdx.x;
    int v = (lane < nb) ? part[lane] : 0;
    int incl = v;
    #pragma unroll
    for (int d = 1; d < 64; d <<= 1) {
        int u = __shfl_up(incl, d, 64);
        if (lane >= d) incl += u;
    }
    if (lane < nb) part[lane] = incl - v;
}

// per-chunk exclusive scan + chunk prefix -> off
__global__ void k_scan_chunks(const int* __restrict__ cnt, const int* __restrict__ part,
                              int* __restrict__ off) {
    __shared__ int wtot[4];
    __shared__ int wexc[4];
    int t = threadIdx.x, b = blockIdx.x;
    int base = b * 2048 + t * 8;
    int4 a = {0, 0, 0, 0}, c = {0, 0, 0, 0};
    if (base < N_NODES) {
        const int4* p = (const int4*)(cnt + base);
        a = p[0];
        c = p[1];
    }
    int s0 = a.x, s1 = s0 + a.y, s2 = s1 + a.z, s3 = s2 + a.w;
    int s4 = s3 + c.x, s5 = s4 + c.y, s6 = s5 + c.z, s7 = s6 + c.w;
    int tot = s7;
    int lane = t & 63, wid = t >> 6;
    int incl = tot;
    #pragma unroll
    for (int d = 1; d < 64; d <<= 1) {
        int u = __shfl_up(incl, d, 64);
        if (lane >= d) incl += u;
    }
    if (lane == 63) wtot[wid] = incl;
    __syncthreads();
    if (t == 0) {
        int r = 0;
        for (int i = 0; i < 4; i++) { int v = wtot[i]; wexc[i] = r; r += v; }
    }
    __syncthreads();
    int texc = incl - tot + wexc[wid] + part[b];
    if (base < N_NODES) {
        int4 o0 = {texc, texc + s0, texc + s1, texc + s2};
        int4 o1 = {texc + s3, texc + s4, texc + s5, texc + s6};
        ((int4*)(off + base))[0] = o0;
        ((int4*)(off + base))[1] = o1;
    }
}

__global__ void k_scatter(const int* __restrict__ dst, const int* __restrict__ off,
                          int* __restrict__ cur, int* __restrict__ eid) {
    int e = blockIdx.x * blockDim.x + threadIdx.x;
    if (e < N_EDGES) {
        int d = dst[e];
        int p = off[d] + atomicAdd(&cur[d], 1);
        eid[p] = e;
    }
}

// ---------------- fused aggregate + 2 GEMMs + epilogue ----------------
// block = 256 threads (4 waves), handles 64 nodes.
// Phase 1: wave w aggregates nodes [w*16, w*16+16): agg[n][0:64] = sum h[src],
//          agg[n][64:128] = sum e.  (lane i owns dim i)
// Phase 2: h_neigh = (W_msg @ agg)/deg + b_msg (or 0 if deg==0)  -> hn LDS
// Phase 3: out = relu(h @ WaH^T + hn @ WaN^T + b_a)
__global__ __launch_bounds__(256) void k_node(
    const float* __restrict__ nf, const float* __restrict__ ef,
    const int* __restrict__ src, const int* __restrict__ cnt,
    const int* __restrict__ off, const int* __restrict__ eid,
    const float* __restrict__ Wm, const float* __restrict__ bm,
    const float* __restrict__ Wa, const float* __restrict__ ba,
    float* __restrict__ out) {
    __shared__ __align__(16) float agg[64][132];  // +4 pad: 4-rows-apart -> bank +16 (2-way, free)
    __shared__ __align__(16) float hn[64][68];
    __shared__ float degl[64];

    int tid = threadIdx.x, lane = tid & 63, wid = tid >> 6;
    int base = blockIdx.x * 64;

    // ---- aggregation ----
    for (int q = 0; q < 16; q++) {
        int nl = wid * 16 + q;
        int n = base + nl;
        float sh = 0.f, se = 0.f;
        int dg = 0;
        if (n < N_NODES) {
            dg = cnt[n];
            int st = off[n];
            for (int c0 = 0; c0 < dg; c0 += 64) {
                int m = dg - c0;
                if (m > 64) m = 64;
                int e_l = 0, s_l = 0;
                if (lane < m) {
                    e_l = eid[st + c0 + lane];
                    s_l = src[e_l];
                }
                // broadcast indices; feature loads are independent -> pipelined
                for (int j = 0; j < m; j++) {
                    int e = __shfl(e_l, j, 64);
                    int s = __shfl(s_l, j, 64);
                    sh += nf[(size_t)s * 64 + lane];
                    se += ef[(size_t)e * 64 + lane];
                }
            }
        }
        agg[nl][lane] = sh;
        agg[nl][64 + lane] = se;
        if (lane == 0) degl[nl] = (float)dg;
    }
    __syncthreads();

    // ---- GEMM1: hn = (Wm @ agg)/deg + bm ----
    int og = (tid & 15) * 4;   // output dim group
    int ng = (tid >> 4) * 4;   // node group
    float acc[4][4] = {};
    const float4* Wm4 = (const float4*)Wm;  // row o = 32 float4
    #pragma unroll 4
    for (int k4 = 0; k4 < 32; k4++) {
        float4 av[4], wv[4];
        #pragma unroll
        for (int i = 0; i < 4; i++) av[i] = *(const float4*)&agg[ng + i][k4 * 4];
        #pragma unroll
        for (int j = 0; j < 4; j++) wv[j] = Wm4[(og + j) * 32 + k4];
        #pragma unroll
        for (int i = 0; i < 4; i++)
            #pragma unroll
            for (int j = 0; j < 4; j++)
                acc[i][j] += av[i].x * wv[j].x + av[i].y * wv[j].y +
                             av[i].z * wv[j].z + av[i].w * wv[j].w;
    }
    #pragma unroll
    for (int i = 0; i < 4; i++) {
        float d = degl[ng + i];
        float inv = (d > 0.f) ? 1.f / d : 0.f;
        #pragma unroll
        for (int j = 0; j < 4; j++) {
            float v = (d > 0.f) ? acc[i][j] * inv + bm[og + j] : 0.f;
            hn[ng + i][og + j] = v;
        }
    }
    __syncthreads();

    // ---- GEMM2: out = relu(h @ WaH^T + hn @ WaN^T + ba) ----
    float acc2[4][4] = {};
    const float4* Wa4 = (const float4*)Wa;  // row o = 32 float4; k<64 -> first 16
    #pragma unroll 4
    for (int k4 = 0; k4 < 16; k4++) {
        float4 hv[4], wv[4];
        #pragma unroll
        for (int i = 0; i < 4; i++) {
            int n = base + ng + i;
            if (n < N_NODES)
                hv[i] = ((const float4*)(nf + (size_t)n * 64))[k4];
            else
                hv[i] = make_float4(0.f, 0.f, 0.f, 0.f);
        }
        #pragma unroll
        for (int j = 0; j < 4; j++) wv[j] = Wa4[(og + j) * 32 + k4];
        #pragma unroll
        for (int i = 0; i < 4; i++)
            #pragma unroll
            for (int j = 0; j < 4; j++)
                acc2[i][j] += hv[i].x * wv[j].x + hv[i].y * wv[j].y +
                              hv[i].z * wv[j].z + hv[i].w * wv[j].w;
    }
    #pragma unroll 4
    for (int k4 = 0; k4 < 16; k4++) {
        float4 hv[4], wv[4];
        #pragma unroll
        for (int i = 0; i < 4; i++) hv[i] = *(const float4*)&hn[ng + i][k4 * 4];
        #pragma unroll
        for (int j = 0; j < 4; j++) wv[j] = Wa4[(og + j) * 32 + 16 + k4];
        #pragma unroll
        for (int i = 0; i < 4; i++)
            #pragma unroll
            for (int j = 0; j < 4; j++)
                acc2[i][j] += hv[i].x * wv[j].x + hv[i].y * wv[j].y +
                              hv[i].z * wv[j].z + hv[i].w * wv[j].w;
    }
    #pragma unroll
    for (int i = 0; i < 4; i++) {
        int n = base + ng + i;
        if (n < N_NODES) {
            float4 o;
            o.x = fmaxf(acc2[i][0] + ba[og + 0], 0.f);
            o.y = fmaxf(acc2[i][1] + ba[og + 1], 0.f);
            o.z = fmaxf(acc2[i][2] + ba[og + 2], 0.f);
            o.w = fmaxf(acc2[i][3] + ba[og + 3], 0.f);
            *(float4*)&out[(size_t)n * 64 + og] = o;
        }
    }
}

extern "C" void kernel_launch(void* const* d_in, const int* in_sizes, int n_in,
                              void* d_out, int out_size, void* d_ws, size_t ws_size,
                              hipStream_t stream) {
    const float* nf = (const float*)d_in[0];
    const float* ef = (const float*)d_in[1];
    const int* src = (const int*)d_in[2];
    const int* dst = (const int*)d_in[3];
    const float* Wm = (const float*)d_in[4];
    const float* bm = (const float*)d_in[5];
    const float* Wa = (const float*)d_in[6];
    const float* ba = (const float*)d_in[7];
    float* out = (float*)d_out;

    // ws layout (ints): cnt[N], off[N], cur[N], part[64], eid[E]  (~7.6 MB)
    int* cnt = (int*)d_ws;
    int* off = cnt + N_NODES;
    int* cur = off + N_NODES;
    int* part = cur + N_NODES;
    int* eid = part + 64;

    int nz = 3 * N_NODES + 64;  // zero cnt, off, cur, part (contiguous)
    k_zero<<<(nz + 255) / 256, 256, 0, stream>>>(cnt, nz);
    k_count<<<(N_EDGES + 255) / 256, 256, 0, stream>>>(dst, cnt);
    k_partial<<<NB_SCAN, 256, 0, stream>>>(cnt, part);
    k_scan_part<<<1, 64, 0, stream>>>(part, NB_SCAN);
    k_scan_chunks<<<NB_SCAN, 256, 0, stream>>>(cnt, part, off);
    k_scatter<<<(N_EDGES + 255) / 256, 256, 0, stream>>>(dst, off, cur, eid);
    k_node<<<(N_NODES + 63) / 64, 256, 0, stream>>>(nf, ef, src, cnt, off, eid,
                                                    Wm, bm, Wa, ba, out);
}